// Round 3
// baseline (348.544 us; speedup 1.0000x reference)
//
#include <hip/hip_runtime.h>
#include <hip/hip_bf16.h>

#define B_ 4
#define C_ 256
#define N_ 4096
#define BN_ (B_*N_)

typedef float f32x4 __attribute__((ext_vector_type(4)));
typedef short bf16x8 __attribute__((ext_vector_type(8)));
typedef short short4v __attribute__((ext_vector_type(4)));

static __device__ __forceinline__ short f2bf(float f){
  unsigned u = __builtin_bit_cast(unsigned, f);
  u += 0x7FFFu + ((u >> 16) & 1u);
  return (short)(u >> 16);
}
static __device__ __forceinline__ float bf2f(short s){
  unsigned u = ((unsigned)(unsigned short)s) << 16;
  return __builtin_bit_cast(float, u);
}
static __device__ __forceinline__ void gload_lds16(const void* g, void* l){
  __builtin_amdgcn_global_load_lds((const __attribute__((address_space(1))) unsigned*)g,
                                   (__attribute__((address_space(3))) unsigned*)l, 16, 0, 0);
}

// ---------------- K1: feat = mean + max over (h,w) ----------------
__global__ __launch_bounds__(256) void k_feat(const float* __restrict__ x, float* __restrict__ feat){
  int row = blockIdx.x; // b*C + c
  const f32x4* p = (const f32x4*)(x + (size_t)row * N_);
  float s = 0.f, mx = -1e30f;
  for (int i = threadIdx.x; i < N_/4; i += 256){
    f32x4 v = p[i];
    s += v.x + v.y + v.z + v.w;
    mx = fmaxf(mx, fmaxf(fmaxf(v.x, v.y), fmaxf(v.z, v.w)));
  }
  __shared__ float ss[256];
  __shared__ float sm[256];
  int t = threadIdx.x;
  ss[t] = s; sm[t] = mx;
  __syncthreads();
  for (int off = 128; off > 0; off >>= 1){
    if (t < off){ ss[t] += ss[t+off]; sm[t] = fmaxf(sm[t], sm[t+off]); }
    __syncthreads();
  }
  if (t == 0) feat[row] = ss[0] * (1.f/(float)N_) + sm[0];
}

// ---------------- K2: complexity gate ----------------
__global__ __launch_bounds__(64) void k_cplx(const float* __restrict__ feat, const float* __restrict__ w1,
    const float* __restrict__ w2, float* __restrict__ cplx){
  int b = blockIdx.x, l = threadIdx.x;
  float contrib = 0.f;
  if (l < 32){
    const float* wr = w1 + l*C_;
    const float* f = feat + b*C_;
    float d = 0.f;
    for (int c = 0; c < C_; c++) d += wr[c]*f[c];
    float sg = 1.f/(1.f + expf(-d));
    contrib = (d*sg)*w2[l];
  }
  #pragma unroll
  for (int off = 1; off < 64; off <<= 1) contrib += __shfl_xor(contrib, off);
  if (l == 0) cplx[b] = 1.f/(1.f + expf(-contrib));
}

// ---------------- K2b: convert weights to bf16 ----------------
__global__ __launch_bounds__(256) void k_wcvt(const float* __restrict__ a, const float* __restrict__ b,
    const float* __restrict__ c, const float* __restrict__ d,
    short* __restrict__ oa, short* __restrict__ ob2, short* __restrict__ oc, short* __restrict__ od){
  int m = blockIdx.x >> 6;
  int off = (blockIdx.x & 63)*1024 + threadIdx.x*4;
  const float* src = (m==0)?a:(m==1)?b:(m==2)?c:d;
  short* dst = (m==0)?oa:(m==1)?ob2:(m==2)?oc:od;
  f32x4 v = *(const f32x4*)(src + off);
  short4v s;
  #pragma unroll
  for (int j = 0; j < 4; j++) s[j] = f2bf(v[j]);
  *(short4v*)(dst + off) = s;
}

// ---------------- K3: fused QKV projection (o-loop inside, x read once) ----------------
__global__ __launch_bounds__(256) void k_qkv(const float* __restrict__ x,
    const short* __restrict__ wqb, const short* __restrict__ wkb, const short* __restrict__ wvb,
    short* __restrict__ Q, short* __restrict__ K, short* __restrict__ Vt){
  int b = blockIdx.y, n0 = blockIdx.x*64;
  int tid = threadIdx.x, w = tid>>6, l = tid&63, lq = l&15, lg = l>>4;
  const float* xb = x + (size_t)b*C_*N_;
  int nrow = n0 + w*16 + lq;
  bf16x8 a[8];
  #pragma unroll
  for (int kk = 0; kk < 8; kk++){
    int c0 = kk*32 + lg*8;
    #pragma unroll
    for (int j = 0; j < 8; j++) a[kk][j] = f2bf(xb[(size_t)(c0+j)*N_ + nrow]);
  }
  __shared__ short lv[64][72];
  f32x4 zero = {0.f,0.f,0.f,0.f};
  for (int ob = 0; ob < 4; ob++){
    f32x4 acc[3][4];
    #pragma unroll
    for (int m = 0; m < 3; m++)
      #pragma unroll
      for (int s = 0; s < 4; s++) acc[m][s] = zero;
    for (int kk = 0; kk < 8; kk++){
      #pragma unroll
      for (int s = 0; s < 4; s++){
        int base = (ob*64 + s*16 + lq)*C_ + kk*32 + lg*8;
        bf16x8 aq = *(const bf16x8*)(wqb + base);
        bf16x8 ak = *(const bf16x8*)(wkb + base);
        bf16x8 av = *(const bf16x8*)(wvb + base);
        acc[0][s] = __builtin_amdgcn_mfma_f32_16x16x32_bf16(a[kk], aq, acc[0][s], 0, 0, 0);
        acc[1][s] = __builtin_amdgcn_mfma_f32_16x16x32_bf16(a[kk], ak, acc[1][s], 0, 0, 0);
        acc[2][s] = __builtin_amdgcn_mfma_f32_16x16x32_bf16(a[kk], av, acc[2][s], 0, 0, 0);
      }
    }
    #pragma unroll
    for (int s = 0; s < 4; s++)
      #pragma unroll
      for (int r = 0; r < 4; r++){
        int n = n0 + w*16 + lg*4 + r;
        int o = ob*64 + s*16 + lq;
        size_t idx = ((size_t)b*N_ + n)*C_ + o;
        Q[idx] = f2bf(acc[0][s][r] * 0.0625f);
        K[idx] = f2bf(acc[1][s][r]);
      }
    __syncthreads();
    #pragma unroll
    for (int s = 0; s < 4; s++)
      #pragma unroll
      for (int r = 0; r < 4; r++)
        lv[s*16 + lq][w*16 + lg*4 + r] = f2bf(acc[2][s][r]);
    __syncthreads();
    #pragma unroll
    for (int i = 0; i < 16; i++){
      int orow = i*4 + (tid>>6);
      int ncol = tid & 63;
      Vt[((size_t)b*C_ + ob*64 + orow)*N_ + n0 + ncol] = lv[orow][ncol];
    }
  }
}

// ---------------- K4: flash attention, 8 waves, KV-split 2-way ----------------
// LDS shorts: Ks[2][16384] | Vs[2][16384] | lp[8][16][72]  = 149504 B
__global__ __launch_bounds__(512) void k_attn(const short* __restrict__ Q, const short* __restrict__ K,
    const short* __restrict__ Vt, short* __restrict__ Op, float* __restrict__ Mp, float* __restrict__ Lp){
  extern __shared__ short smem[];
  short* Ks = smem;
  short* Vs = smem + 32768;

  int bid = blockIdx.x;
  int xcd = bid & 7;
  int b = xcd >> 1;
  int half = xcd & 1;
  int n0 = (bid >> 3) * 128;
  int kv0 = half * 2048;
  int tid = threadIdx.x, w = tid>>6, l = tid&63, lq = l&15, lg = l>>4;
  const short* Qb = Q + (size_t)b*N_*C_;
  const short* Kb = K + (size_t)b*N_*C_;
  const short* Vb = Vt + (size_t)b*C_*N_;
  short* lp = smem + 65536 + w*(16*72);

  int krow0 = w*8 + (l>>5);
  int kchunk0 = l&31;
  int vrow0 = w*32 + (l>>3);
  int vchunk = (l&7) ^ ((l>>3)&7);

  bf16x8 qf[8];
  {
    const short* qrow = Qb + (size_t)(n0 + w*16 + lq)*C_ + lg*8;
    #pragma unroll
    for (int kk = 0; kk < 8; kk++) qf[kk] = *(const bf16x8*)(qrow + kk*32);
  }
  f32x4 zero = {0.f,0.f,0.f,0.f};
  f32x4 oacc[16];
  #pragma unroll
  for (int c = 0; c < 16; c++) oacc[c] = zero;
  float mrow[4], lsum[4];
  #pragma unroll
  for (int r = 0; r < 4; r++){ mrow[r] = -1e30f; lsum[r] = 0.f; }

  int swz = lq & 7;

  auto stage = [&](int buf, int m0){
    short* kd = Ks + buf*16384 + w*2048;
    short* vd = Vs + buf*16384 + w*2048;
    #pragma unroll
    for (int i = 0; i < 4; i++){
      int row = krow0 + i*2;
      int chunk = kchunk0 ^ (row & 7);
      gload_lds16(Kb + (size_t)(m0 + row)*C_ + chunk*8, kd + i*512);
    }
    #pragma unroll
    for (int i = 0; i < 4; i++){
      int row = vrow0 + i*8;
      gload_lds16(Vb + (size_t)row*N_ + m0 + vchunk*8, vd + i*512);
    }
  };

  stage(0, kv0);
  __syncthreads();
  int cur = 0;

  for (int mt = 0; mt < 32; mt++){
    if (mt + 1 < 32) stage(cur^1, kv0 + (mt+1)*64);

    const short* Kc = Ks + cur*16384;
    const short* Vc = Vs + cur*16384;

    f32x4 sa[4];
    #pragma unroll
    for (int s = 0; s < 4; s++) sa[s] = zero;
    #pragma unroll
    for (int s = 0; s < 4; s++){
      const short* krowp = Kc + (s*16 + lq)*256;
      #pragma unroll
      for (int kk = 0; kk < 8; kk++){
        bf16x8 kf = *(const bf16x8*)(krowp + (((kk*4 + lg) ^ swz) << 3));
        sa[s] = __builtin_amdgcn_mfma_f32_16x16x32_bf16(qf[kk], kf, sa[s], 0, 0, 0);
      }
    }
    float al[4];
    #pragma unroll
    for (int r = 0; r < 4; r++){
      float t = fmaxf(fmaxf(sa[0][r], sa[1][r]), fmaxf(sa[2][r], sa[3][r]));
      t = fmaxf(t, __shfl_xor(t, 1));
      t = fmaxf(t, __shfl_xor(t, 2));
      t = fmaxf(t, __shfl_xor(t, 4));
      t = fmaxf(t, __shfl_xor(t, 8));
      float mn = fmaxf(mrow[r], t);
      al[r] = __expf(mrow[r] - mn);
      mrow[r] = mn;
    }
    #pragma unroll
    for (int s = 0; s < 4; s++)
      #pragma unroll
      for (int r = 0; r < 4; r++)
        sa[s][r] = __expf(sa[s][r] - mrow[r]);
    #pragma unroll
    for (int r = 0; r < 4; r++){
      float t = sa[0][r] + sa[1][r] + sa[2][r] + sa[3][r];
      t += __shfl_xor(t, 1); t += __shfl_xor(t, 2);
      t += __shfl_xor(t, 4); t += __shfl_xor(t, 8);
      lsum[r] = lsum[r]*al[r] + t;
    }
    #pragma unroll
    for (int c = 0; c < 16; c++){
      f32x4 o = oacc[c];
      o[0]*=al[0]; o[1]*=al[1]; o[2]*=al[2]; o[3]*=al[3];
      oacc[c] = o;
    }
    #pragma unroll
    for (int s = 0; s < 4; s++)
      #pragma unroll
      for (int r = 0; r < 4; r++)
        lp[(lg*4 + r)*72 + s*16 + lq] = f2bf(sa[s][r]);
    __builtin_amdgcn_sched_barrier(0);
    #pragma unroll
    for (int s2 = 0; s2 < 2; s2++){
      bf16x8 pa = *(const bf16x8*)(lp + lq*72 + s2*32 + lg*8);
      #pragma unroll
      for (int c = 0; c < 16; c++){
        bf16x8 vbf = *(const bf16x8*)(Vc + (c*16 + lq)*64 + (((s2*4 + lg) ^ swz) << 3));
        oacc[c] = __builtin_amdgcn_mfma_f32_16x16x32_bf16(pa, vbf, oacc[c], 0, 0, 0);
      }
    }
    __builtin_amdgcn_sched_barrier(0);
    __syncthreads();
    cur ^= 1;
  }
  float inv[4];
  #pragma unroll
  for (int r = 0; r < 4; r++) inv[r] = 1.f / lsum[r];
  #pragma unroll
  for (int c = 0; c < 16; c++)
    #pragma unroll
    for (int r = 0; r < 4; r++){
      int n = n0 + w*16 + lg*4 + r;
      Op[((size_t)half*BN_ + (size_t)b*N_ + n)*C_ + c*16 + lq] = f2bf(oacc[c][r]*inv[r]);
    }
  if (lq == 0){
    #pragma unroll
    for (int r = 0; r < 4; r++){
      int n = n0 + w*16 + lg*4 + r;
      Mp[half*BN_ + b*N_ + n] = mrow[r];
      Lp[half*BN_ + b*N_ + n] = lsum[r];
    }
  }
}

// ---------------- K4b: combine the two KV halves ----------------
__global__ __launch_bounds__(256) void k_comb(const short* __restrict__ Op, const float* __restrict__ Mp,
    const float* __restrict__ Lp, short* __restrict__ Xa){
  int tid = threadIdx.x;
  int rg = blockIdx.x*8 + (tid>>5);
  int cc = (tid&31)*8;
  float m1 = Mp[rg], m2 = Mp[BN_ + rg];
  float l1 = Lp[rg], l2 = Lp[BN_ + rg];
  float m = fmaxf(m1, m2);
  float w1 = l1 * __expf(m1 - m);
  float w2 = l2 * __expf(m2 - m);
  float inv = 1.f/(w1 + w2);
  w1 *= inv; w2 *= inv;
  bf16x8 o1 = *(const bf16x8*)(Op + (size_t)rg*C_ + cc);
  bf16x8 o2 = *(const bf16x8*)(Op + ((size_t)BN_ + rg)*C_ + cc);
  bf16x8 r;
  #pragma unroll
  for (int j = 0; j < 8; j++){
    float f = w1*bf2f(o1[j]) + w2*bf2f(o2[j]);
    r[j] = f2bf(f);
  }
  *(bf16x8*)(Xa + (size_t)rg*C_ + cc) = r;
}

// ---------------- K5: out = x + cplx * (wproj @ x_attn^T), o-loop inside ----------------
__global__ __launch_bounds__(256) void k_proj(const float* __restrict__ x, const short* __restrict__ wpb,
    const short* __restrict__ Xa, const float* __restrict__ cplx, float* __restrict__ out){
  int b = blockIdx.y, n0 = blockIdx.x*64;
  int tid = threadIdx.x, w = tid>>6, l = tid&63, lq = l&15, lg = l>>4;
  bf16x8 xa[4][8];
  #pragma unroll
  for (int s = 0; s < 4; s++)
    #pragma unroll
    for (int kk = 0; kk < 8; kk++)
      xa[s][kk] = *(const bf16x8*)(Xa + ((size_t)b*N_ + n0 + s*16 + lq)*C_ + kk*32 + lg*8);
  float cp = cplx[b];
  f32x4 zero = {0.f,0.f,0.f,0.f};
  for (int ob = 0; ob < 4; ob++){
    f32x4 acc[4];
    #pragma unroll
    for (int s = 0; s < 4; s++) acc[s] = zero;
    for (int kk = 0; kk < 8; kk++){
      bf16x8 aw = *(const bf16x8*)(wpb + (ob*64 + w*16 + lq)*C_ + kk*32 + lg*8);
      #pragma unroll
      for (int s = 0; s < 4; s++)
        acc[s] = __builtin_amdgcn_mfma_f32_16x16x32_bf16(aw, xa[s][kk], acc[s], 0, 0, 0);
    }
    #pragma unroll
    for (int s = 0; s < 4; s++)
      #pragma unroll
      for (int r = 0; r < 4; r++){
        int o = ob*64 + w*16 + lg*4 + r;
        int n = n0 + s*16 + lq;
        size_t idx = ((size_t)b*C_ + o)*N_ + n;
        out[idx] = x[idx] + cp*acc[s][r];
      }
  }
}

extern "C" void kernel_launch(void* const* d_in, const int* in_sizes, int n_in,
                              void* d_out, int out_size, void* d_ws, size_t ws_size,
                              hipStream_t stream){
  const float* x     = (const float*)d_in[0];
  const float* w_ce1 = (const float*)d_in[1];
  const float* w_ce2 = (const float*)d_in[2];
  const float* wq    = (const float*)d_in[3];
  const float* wk    = (const float*)d_in[4];
  const float* wv    = (const float*)d_in[5];
  const float* wproj = (const float*)d_in[6];
  float* out = (float*)d_out;

  const size_t mat = (size_t)B_*N_*C_;
  short* Q   = (short*)d_ws;
  short* K   = Q + mat;
  short* Vt  = K + mat;
  short* Op  = Vt + mat;              // 2*mat (bf16 partials, both halves)
  float* Mp  = (float*)(Op + 2*mat);  // 2*BN_
  float* Lp  = Mp + 2*BN_;
  float* feat= Lp + 2*BN_;
  float* cplx= feat + B_*C_;
  short* wqb = (short*)(cplx + B_);
  short* wkb = wqb + C_*C_;
  short* wvb = wkb + C_*C_;
  short* wpb = wvb + C_*C_;
  short* Xa  = Q;                     // alias: Q dead after k_attn

  const int SMEM_ATTN = (16384*2 + 16384*2 + 8*16*72) * 2; // 149504 B
  hipFuncSetAttribute((const void*)k_attn, hipFuncAttributeMaxDynamicSharedMemorySize, SMEM_ATTN);

  hipLaunchKernelGGL(k_feat, dim3(B_*C_), dim3(256), 0, stream, x, feat);
  hipLaunchKernelGGL(k_cplx, dim3(B_), dim3(64), 0, stream, feat, w_ce1, w_ce2, cplx);
  hipLaunchKernelGGL(k_wcvt, dim3(256), dim3(256), 0, stream, wq, wk, wv, wproj, wqb, wkb, wvb, wpb);
  hipLaunchKernelGGL(k_qkv, dim3(64,4), dim3(256), 0, stream, x, wqb, wkb, wvb, Q, K, Vt);
  hipLaunchKernelGGL(k_attn, dim3(256), dim3(512), SMEM_ATTN, stream, Q, K, Vt, Op, Mp, Lp);
  hipLaunchKernelGGL(k_comb, dim3(BN_/8), dim3(256), 0, stream, Op, Mp, Lp, Xa);
  hipLaunchKernelGGL(k_proj, dim3(64,4), dim3(256), 0, stream, x, wpb, Xa, cplx, out);
}

// Round 4
// 209.587 us; speedup vs baseline: 1.6630x; 1.6630x over previous
//
#include <hip/hip_runtime.h>
#include <hip/hip_bf16.h>

#define B_ 4
#define C_ 256
#define N_ 4096
#define BN_ (B_*N_)

typedef float f32x4 __attribute__((ext_vector_type(4)));
typedef short bf16x8 __attribute__((ext_vector_type(8)));
typedef short short4v __attribute__((ext_vector_type(4)));

static __device__ __forceinline__ short f2bf(float f){
  unsigned u = __builtin_bit_cast(unsigned, f);
  u += 0x7FFFu + ((u >> 16) & 1u);
  return (short)(u >> 16);
}
static __device__ __forceinline__ float bf2f(short s){
  unsigned u = ((unsigned)(unsigned short)s) << 16;
  return __builtin_bit_cast(float, u);
}
static __device__ __forceinline__ void gload_lds16(const void* g, void* l){
  __builtin_amdgcn_global_load_lds((const __attribute__((address_space(1))) unsigned*)g,
                                   (__attribute__((address_space(3))) unsigned*)l, 16, 0, 0);
}

// ---------------- K1: feat = mean + max over (h,w) ----------------
__global__ __launch_bounds__(256) void k_feat(const float* __restrict__ x, float* __restrict__ feat){
  int row = blockIdx.x; // b*C + c
  const f32x4* p = (const f32x4*)(x + (size_t)row * N_);
  float s = 0.f, mx = -1e30f;
  for (int i = threadIdx.x; i < N_/4; i += 256){
    f32x4 v = p[i];
    s += v.x + v.y + v.z + v.w;
    mx = fmaxf(mx, fmaxf(fmaxf(v.x, v.y), fmaxf(v.z, v.w)));
  }
  __shared__ float ss[256];
  __shared__ float sm[256];
  int t = threadIdx.x;
  ss[t] = s; sm[t] = mx;
  __syncthreads();
  for (int off = 128; off > 0; off >>= 1){
    if (t < off){ ss[t] += ss[t+off]; sm[t] = fmaxf(sm[t], sm[t+off]); }
    __syncthreads();
  }
  if (t == 0) feat[row] = ss[0] * (1.f/(float)N_) + sm[0];
}

// ---------------- K2: complexity gate ----------------
__global__ __launch_bounds__(64) void k_cplx(const float* __restrict__ feat, const float* __restrict__ w1,
    const float* __restrict__ w2, float* __restrict__ cplx){
  int b = blockIdx.x, l = threadIdx.x;
  float contrib = 0.f;
  if (l < 32){
    const float* wr = w1 + l*C_;
    const float* f = feat + b*C_;
    float d = 0.f;
    for (int c = 0; c < C_; c++) d += wr[c]*f[c];
    float sg = 1.f/(1.f + expf(-d));
    contrib = (d*sg)*w2[l];
  }
  #pragma unroll
  for (int off = 1; off < 64; off <<= 1) contrib += __shfl_xor(contrib, off);
  if (l == 0) cplx[b] = 1.f/(1.f + expf(-contrib));
}

// ---------------- K2b: convert weights to bf16 ----------------
__global__ __launch_bounds__(256) void k_wcvt(const float* __restrict__ a, const float* __restrict__ b,
    const float* __restrict__ c, const float* __restrict__ d,
    short* __restrict__ oa, short* __restrict__ ob2, short* __restrict__ oc, short* __restrict__ od){
  int m = blockIdx.x >> 6;
  int off = (blockIdx.x & 63)*1024 + threadIdx.x*4;
  const float* src = (m==0)?a:(m==1)?b:(m==2)?c:d;
  short* dst = (m==0)?oa:(m==1)?ob2:(m==2)?oc:od;
  f32x4 v = *(const f32x4*)(src + off);
  short4v s;
  #pragma unroll
  for (int j = 0; j < 4; j++) s[j] = f2bf(v[j]);
  *(short4v*)(dst + off) = s;
}

// ---------------- K3: fused QKV projection (1024 blocks, bf16 weights) ----------------
__global__ __launch_bounds__(256) void k_qkv(const float* __restrict__ x,
    const short* __restrict__ wqb, const short* __restrict__ wkb, const short* __restrict__ wvb,
    short* __restrict__ Q, short* __restrict__ K, short* __restrict__ Vt){
  int b = blockIdx.z, o0 = blockIdx.y*64, n0 = blockIdx.x*64;
  int tid = threadIdx.x, w = tid>>6, l = tid&63, lq = l&15, lg = l>>4;
  const float* xb = x + (size_t)b*C_*N_;
  int nrow = n0 + w*16 + lq;
  f32x4 zero = {0.f,0.f,0.f,0.f};
  f32x4 acc[3][4];
  #pragma unroll
  for (int m = 0; m < 3; m++)
    #pragma unroll
    for (int s = 0; s < 4; s++) acc[m][s] = zero;

  for (int kk = 0; kk < 8; ++kk){
    int c0 = kk*32 + lg*8;
    bf16x8 a;
    #pragma unroll
    for (int j = 0; j < 8; j++) a[j] = f2bf(xb[(size_t)(c0+j)*N_ + nrow]);
    #pragma unroll
    for (int s = 0; s < 4; s++){
      int base = (o0 + s*16 + lq)*C_ + c0;
      bf16x8 aq = *(const bf16x8*)(wqb + base);
      bf16x8 ak = *(const bf16x8*)(wkb + base);
      bf16x8 av = *(const bf16x8*)(wvb + base);
      acc[0][s] = __builtin_amdgcn_mfma_f32_16x16x32_bf16(a, aq, acc[0][s], 0, 0, 0);
      acc[1][s] = __builtin_amdgcn_mfma_f32_16x16x32_bf16(a, ak, acc[1][s], 0, 0, 0);
      acc[2][s] = __builtin_amdgcn_mfma_f32_16x16x32_bf16(a, av, acc[2][s], 0, 0, 0);
    }
  }
  #pragma unroll
  for (int s = 0; s < 4; s++)
    #pragma unroll
    for (int r = 0; r < 4; r++){
      int n = n0 + w*16 + lg*4 + r;
      int o = o0 + s*16 + lq;
      size_t idx = ((size_t)b*N_ + n)*C_ + o;
      Q[idx] = f2bf(acc[0][s][r] * 0.0625f);
      K[idx] = f2bf(acc[1][s][r]);
    }
  __shared__ short lv[64][72];
  #pragma unroll
  for (int s = 0; s < 4; s++)
    #pragma unroll
    for (int r = 0; r < 4; r++)
      lv[s*16 + lq][w*16 + lg*4 + r] = f2bf(acc[2][s][r]);
  __syncthreads();
  #pragma unroll
  for (int i = 0; i < 16; i++){
    int orow = i*4 + (tid>>6);
    int ncol = tid & 63;
    Vt[((size_t)b*C_ + o0 + orow)*N_ + n0 + ncol] = lv[orow][ncol];
  }
}

// ---------------- K4: flash attention, 8 waves, KV-split 2-way ----------------
// LDS shorts: Ks[2][16384] | Vs[2][16384] | lp[8][16][72]  = 149504 B
__global__ __launch_bounds__(512) void k_attn(const short* __restrict__ Q, const short* __restrict__ K,
    const short* __restrict__ Vt, short* __restrict__ Op, float* __restrict__ Mp, float* __restrict__ Lp){
  extern __shared__ short smem[];
  short* Ks = smem;
  short* Vs = smem + 32768;

  int bid = blockIdx.x;
  int xcd = bid & 7;
  int b = xcd >> 1;
  int half = xcd & 1;
  int n0 = (bid >> 3) * 128;
  int kv0 = half * 2048;
  int tid = threadIdx.x, w = tid>>6, l = tid&63, lq = l&15, lg = l>>4;
  const short* Qb = Q + (size_t)b*N_*C_;
  const short* Kb = K + (size_t)b*N_*C_;
  const short* Vb = Vt + (size_t)b*C_*N_;
  short* lp = smem + 65536 + w*(16*72);

  int krow0 = w*8 + (l>>5);
  int kchunk0 = l&31;
  int vrow0 = w*32 + (l>>3);
  int vchunk = (l&7) ^ ((l>>3)&7);

  bf16x8 qf[8];
  {
    const short* qrow = Qb + (size_t)(n0 + w*16 + lq)*C_ + lg*8;
    #pragma unroll
    for (int kk = 0; kk < 8; kk++) qf[kk] = *(const bf16x8*)(qrow + kk*32);
  }
  f32x4 zero = {0.f,0.f,0.f,0.f};
  f32x4 oacc[16];
  #pragma unroll
  for (int c = 0; c < 16; c++) oacc[c] = zero;
  float mrow[4], lsum[4];
  #pragma unroll
  for (int r = 0; r < 4; r++){ mrow[r] = -1e30f; lsum[r] = 0.f; }

  int swz = lq & 7;

  auto stage = [&](int buf, int m0){
    short* kd = Ks + buf*16384 + w*2048;
    short* vd = Vs + buf*16384 + w*2048;
    #pragma unroll
    for (int i = 0; i < 4; i++){
      int row = krow0 + i*2;
      int chunk = kchunk0 ^ (row & 7);
      gload_lds16(Kb + (size_t)(m0 + row)*C_ + chunk*8, kd + i*512);
    }
    #pragma unroll
    for (int i = 0; i < 4; i++){
      int row = vrow0 + i*8;
      gload_lds16(Vb + (size_t)row*N_ + m0 + vchunk*8, vd + i*512);
    }
  };

  stage(0, kv0);
  __syncthreads();
  int cur = 0;

  for (int mt = 0; mt < 32; mt++){
    if (mt + 1 < 32) stage(cur^1, kv0 + (mt+1)*64);

    const short* Kc = Ks + cur*16384;
    const short* Vc = Vs + cur*16384;

    f32x4 sa[4];
    #pragma unroll
    for (int s = 0; s < 4; s++) sa[s] = zero;
    __builtin_amdgcn_s_setprio(1);
    #pragma unroll
    for (int s = 0; s < 4; s++){
      const short* krowp = Kc + (s*16 + lq)*256;
      #pragma unroll
      for (int kk = 0; kk < 8; kk++){
        bf16x8 kf = *(const bf16x8*)(krowp + (((kk*4 + lg) ^ swz) << 3));
        sa[s] = __builtin_amdgcn_mfma_f32_16x16x32_bf16(qf[kk], kf, sa[s], 0, 0, 0);
      }
    }
    __builtin_amdgcn_s_setprio(0);
    // tile row max (16-lane groups hold a row)
    float tmax[4];
    #pragma unroll
    for (int r = 0; r < 4; r++){
      float t = fmaxf(fmaxf(sa[0][r], sa[1][r]), fmaxf(sa[2][r], sa[3][r]));
      t = fmaxf(t, __shfl_xor(t, 1));
      t = fmaxf(t, __shfl_xor(t, 2));
      t = fmaxf(t, __shfl_xor(t, 4));
      t = fmaxf(t, __shfl_xor(t, 8));
      tmax[r] = t;
    }
    // T13 defer-max: only rescale when max grew by >8
    bool need = (tmax[0] > mrow[0]+8.f) | (tmax[1] > mrow[1]+8.f) |
                (tmax[2] > mrow[2]+8.f) | (tmax[3] > mrow[3]+8.f);
    if (__any(need)){
      float al[4];
      #pragma unroll
      for (int r = 0; r < 4; r++){
        float mn = fmaxf(mrow[r], tmax[r]);
        al[r] = __expf(mrow[r] - mn);
        mrow[r] = mn;
        lsum[r] *= al[r];
      }
      #pragma unroll
      for (int c = 0; c < 16; c++){
        f32x4 o = oacc[c];
        o[0]*=al[0]; o[1]*=al[1]; o[2]*=al[2]; o[3]*=al[3];
        oacc[c] = o;
      }
    }
    #pragma unroll
    for (int s = 0; s < 4; s++)
      #pragma unroll
      for (int r = 0; r < 4; r++)
        sa[s][r] = __expf(sa[s][r] - mrow[r]);
    #pragma unroll
    for (int r = 0; r < 4; r++){
      float t = sa[0][r] + sa[1][r] + sa[2][r] + sa[3][r];
      t += __shfl_xor(t, 1); t += __shfl_xor(t, 2);
      t += __shfl_xor(t, 4); t += __shfl_xor(t, 8);
      lsum[r] += t;
    }
    #pragma unroll
    for (int s = 0; s < 4; s++)
      #pragma unroll
      for (int r = 0; r < 4; r++)
        lp[(lg*4 + r)*72 + s*16 + lq] = f2bf(sa[s][r]);
    __builtin_amdgcn_sched_barrier(0);
    __builtin_amdgcn_s_setprio(1);
    #pragma unroll
    for (int s2 = 0; s2 < 2; s2++){
      bf16x8 pa = *(const bf16x8*)(lp + lq*72 + s2*32 + lg*8);
      #pragma unroll
      for (int c = 0; c < 16; c++){
        bf16x8 vbf = *(const bf16x8*)(Vc + (c*16 + lq)*64 + (((s2*4 + lg) ^ swz) << 3));
        oacc[c] = __builtin_amdgcn_mfma_f32_16x16x32_bf16(pa, vbf, oacc[c], 0, 0, 0);
      }
    }
    __builtin_amdgcn_s_setprio(0);
    __builtin_amdgcn_sched_barrier(0);
    __syncthreads();
    cur ^= 1;
  }
  float inv[4];
  #pragma unroll
  for (int r = 0; r < 4; r++) inv[r] = 1.f / lsum[r];
  #pragma unroll
  for (int c = 0; c < 16; c++)
    #pragma unroll
    for (int r = 0; r < 4; r++){
      int n = n0 + w*16 + lg*4 + r;
      Op[((size_t)half*BN_ + (size_t)b*N_ + n)*C_ + c*16 + lq] = f2bf(oacc[c][r]*inv[r]);
    }
  if (lq == 0){
    #pragma unroll
    for (int r = 0; r < 4; r++){
      int n = n0 + w*16 + lg*4 + r;
      Mp[half*BN_ + b*N_ + n] = mrow[r];
      Lp[half*BN_ + b*N_ + n] = lsum[r];
    }
  }
}

// ---------------- K4b: combine the two KV halves ----------------
__global__ __launch_bounds__(256) void k_comb(const short* __restrict__ Op, const float* __restrict__ Mp,
    const float* __restrict__ Lp, short* __restrict__ Xa){
  int tid = threadIdx.x;
  int rg = blockIdx.x*8 + (tid>>5);
  int cc = (tid&31)*8;
  float m1 = Mp[rg], m2 = Mp[BN_ + rg];
  float l1 = Lp[rg], l2 = Lp[BN_ + rg];
  float m = fmaxf(m1, m2);
  float w1 = l1 * __expf(m1 - m);
  float w2 = l2 * __expf(m2 - m);
  float inv = 1.f/(w1 + w2);
  w1 *= inv; w2 *= inv;
  bf16x8 o1 = *(const bf16x8*)(Op + (size_t)rg*C_ + cc);
  bf16x8 o2 = *(const bf16x8*)(Op + ((size_t)BN_ + rg)*C_ + cc);
  bf16x8 r;
  #pragma unroll
  for (int j = 0; j < 8; j++){
    float f = w1*bf2f(o1[j]) + w2*bf2f(o2[j]);
    r[j] = f2bf(f);
  }
  *(bf16x8*)(Xa + (size_t)rg*C_ + cc) = r;
}

// ---------------- K5: out = x + cplx * (wproj @ x_attn^T), 1024 blocks ----------------
__global__ __launch_bounds__(256) void k_proj(const float* __restrict__ x, const short* __restrict__ wpb,
    const short* __restrict__ Xa, const float* __restrict__ cplx, float* __restrict__ out){
  int b = blockIdx.z, o0 = blockIdx.y*64, n0 = blockIdx.x*64;
  int tid = threadIdx.x, w = tid>>6, l = tid&63, lq = l&15, lg = l>>4;
  f32x4 zero = {0.f,0.f,0.f,0.f};
  f32x4 acc[4];
  #pragma unroll
  for (int s = 0; s < 4; s++) acc[s] = zero;
  int orow = o0 + w*16 + lq;
  for (int kk = 0; kk < 8; kk++){
    int c0 = kk*32 + lg*8;
    bf16x8 aw = *(const bf16x8*)(wpb + orow*C_ + c0);
    #pragma unroll
    for (int s = 0; s < 4; s++){
      bf16x8 xb = *(const bf16x8*)(Xa + ((size_t)b*N_ + n0 + s*16 + lq)*C_ + c0);
      acc[s] = __builtin_amdgcn_mfma_f32_16x16x32_bf16(aw, xb, acc[s], 0, 0, 0);
    }
  }
  float cp = cplx[b];
  #pragma unroll
  for (int s = 0; s < 4; s++)
    #pragma unroll
    for (int r = 0; r < 4; r++){
      int o = o0 + w*16 + lg*4 + r;
      int n = n0 + s*16 + lq;
      size_t idx = ((size_t)b*C_ + o)*N_ + n;
      out[idx] = x[idx] + cp*acc[s][r];
    }
}

extern "C" void kernel_launch(void* const* d_in, const int* in_sizes, int n_in,
                              void* d_out, int out_size, void* d_ws, size_t ws_size,
                              hipStream_t stream){
  const float* x     = (const float*)d_in[0];
  const float* w_ce1 = (const float*)d_in[1];
  const float* w_ce2 = (const float*)d_in[2];
  const float* wq    = (const float*)d_in[3];
  const float* wk    = (const float*)d_in[4];
  const float* wv    = (const float*)d_in[5];
  const float* wproj = (const float*)d_in[6];
  float* out = (float*)d_out;

  const size_t mat = (size_t)B_*N_*C_;
  short* Q   = (short*)d_ws;
  short* K   = Q + mat;
  short* Vt  = K + mat;
  short* Op  = Vt + mat;              // 2*mat (bf16 partials, both halves)
  float* Mp  = (float*)(Op + 2*mat);  // 2*BN_
  float* Lp  = Mp + 2*BN_;
  float* feat= Lp + 2*BN_;
  float* cplx= feat + B_*C_;
  short* wqb = (short*)(cplx + B_);
  short* wkb = wqb + C_*C_;
  short* wvb = wkb + C_*C_;
  short* wpb = wvb + C_*C_;
  short* Xa  = Q;                     // alias: Q dead after k_attn

  const int SMEM_ATTN = (16384*2 + 16384*2 + 8*16*72) * 2; // 149504 B
  hipFuncSetAttribute((const void*)k_attn, hipFuncAttributeMaxDynamicSharedMemorySize, SMEM_ATTN);

  hipLaunchKernelGGL(k_feat, dim3(B_*C_), dim3(256), 0, stream, x, feat);
  hipLaunchKernelGGL(k_cplx, dim3(B_), dim3(64), 0, stream, feat, w_ce1, w_ce2, cplx);
  hipLaunchKernelGGL(k_wcvt, dim3(256), dim3(256), 0, stream, wq, wk, wv, wproj, wqb, wkb, wvb, wpb);
  hipLaunchKernelGGL(k_qkv, dim3(64,4,4), dim3(256), 0, stream, x, wqb, wkb, wvb, Q, K, Vt);
  hipLaunchKernelGGL(k_attn, dim3(256), dim3(512), SMEM_ATTN, stream, Q, K, Vt, Op, Mp, Lp);
  hipLaunchKernelGGL(k_comb, dim3(BN_/8), dim3(256), 0, stream, Op, Mp, Lp, Xa);
  hipLaunchKernelGGL(k_proj, dim3(64,4,4), dim3(256), 0, stream, x, wpb, Xa, cplx, out);
}